// Round 9
// baseline (236.521 us; speedup 1.0000x reference)
//
#include <hip/hip_runtime.h>
#include <hip/hip_bf16.h>
#include <math.h>

#define N_ROWS 4096
#define DIM    512
#define M_ROWS 8192
// sim GEMM: 128x128 tiles, 4 waves (2x2 of 64x64), NO LDS:
// reps @ reps^T is symmetric-layout -> both MFMA fragments are direct
// 16B-per-lane row-chunks of reps; load global->reg, skip staging entirely.
#define BK     32
#define NTILE  64            // 8192 / 128
#define NB     2080          // 64*65/2 triangular tiles (2080 % 8 == 0)
#define NSTEP  16            // 512 / 32
// exp(sim/0.1) = exp2(sim * 10*log2(e))
#define EXP_SCALE 14.4269504088896340736f

typedef unsigned short ushort_t;
typedef __attribute__((ext_vector_type(8))) short short8;
typedef __attribute__((ext_vector_type(4))) float f32x4;

__device__ __forceinline__ ushort_t f2bf(float x) {
  unsigned int bits = __float_as_uint(x);
  unsigned int lsb = (bits >> 16) & 1u;
  bits += 0x7fffu + lsb;
  return (ushort_t)(bits >> 16);
}

__device__ __forceinline__ void store4bf(ushort_t* p, float4 v, float s) {
  union { ushort_t u[4]; uint2 d; } pk;
  pk.u[0] = f2bf(v.x * s);
  pk.u[1] = f2bf(v.y * s);
  pk.u[2] = f2bf(v.z * s);
  pk.u[3] = f2bf(v.w * s);
  *(uint2*)p = pk.d;
}

// ---------------------------------------------------------------------------
// Kernel 1: per-row L2 normalize; 256-thread blocks, one wave per row-pair.
// Also zeroes denom[].
// ---------------------------------------------------------------------------
__global__ __launch_bounds__(256) void norm_kernel(
    const float* __restrict__ ei, const float* __restrict__ ej,
    ushort_t* __restrict__ reps, float* __restrict__ pos,
    float* __restrict__ denom) {
  int wave = threadIdx.x >> 6;
  int lane = threadIdx.x & 63;
  int b = blockIdx.x * 4 + wave;
  if (lane == 0) {
    denom[b] = 0.0f;
    denom[b + N_ROWS] = 0.0f;
  }
  const float4* pi = (const float4*)(ei + (size_t)b * DIM);
  const float4* pj = (const float4*)(ej + (size_t)b * DIM);
  float4 a0 = pi[lane];
  float4 a1 = pi[lane + 64];
  float4 b0 = pj[lane];
  float4 b1 = pj[lane + 64];

  float si = a0.x*a0.x + a0.y*a0.y + a0.z*a0.z + a0.w*a0.w
           + a1.x*a1.x + a1.y*a1.y + a1.z*a1.z + a1.w*a1.w;
  float sj = b0.x*b0.x + b0.y*b0.y + b0.z*b0.z + b0.w*b0.w
           + b1.x*b1.x + b1.y*b1.y + b1.z*b1.z + b1.w*b1.w;
  float dp = a0.x*b0.x + a0.y*b0.y + a0.z*b0.z + a0.w*b0.w
           + a1.x*b1.x + a1.y*b1.y + a1.z*b1.z + a1.w*b1.w;

#pragma unroll
  for (int m = 32; m >= 1; m >>= 1) {
    si += __shfl_xor(si, m, 64);
    sj += __shfl_xor(sj, m, 64);
    dp += __shfl_xor(dp, m, 64);
  }
  float ii = 1.0f / fmaxf(sqrtf(si), 1e-12f);
  float ij = 1.0f / fmaxf(sqrtf(sj), 1e-12f);
  if (lane == 0) pos[b] = dp * ii * ij;

  ushort_t* ri = reps + (size_t)b * DIM;
  ushort_t* rj = reps + (size_t)(b + N_ROWS) * DIM;
  store4bf(ri + lane * 4,       a0, ii);
  store4bf(ri + 256 + lane * 4, a1, ii);
  store4bf(rj + lane * 4,       b0, ij);
  store4bf(rj + 256 + lane * 4, b1, ij);
}

// ---------------------------------------------------------------------------
// Kernel 2: 128x128-tile fused sim-GEMM + exp + masked row/col reduction.
// Rounds 1-8 post-mortem: duration pinned at 73-82 us across tile size,
// staged bytes, cache locality, schedule, and occupancy -> the shared
// limiter is the global->LDS->reg staging path itself (~7.3 TB/s service).
// This round: ELIMINATE LDS. reps@reps^T has no transpose: the MFMA A- and
// B-fragments are reps[row][kk*32 + quad*8 ..+8] directly -- a 16B-per-lane
// global load (64B x 16 rows per instr, same coalescing as staging). Each
// wave loads its 8 fragments/step global->reg, double-buffered:
// zero barriers, zero LDS, fully independent waves. Content provably equals
// the LDS version's fragments (which scored absmax=0).
// Keeps super-tile blob order + chunked XCD remap (staging is L2-served).
// ---------------------------------------------------------------------------
__global__ __launch_bounds__(256) void sim_kernel(
    const ushort_t* __restrict__ reps, float* __restrict__ denom) {
  // chunked XCD remap: XCD x owns logical ids [x*260, (x+1)*260)
  int id = blockIdx.x;
  id = (id & 7) * (NB / 8) + (id >> 3);

  // super-tile blob decode: 4x4 super grid (16x16 tiles each), sj-major,
  // si<=sj; diag super = 136 tiles (16x16 triangle), off-diag = 256.
  int bi, bj;
  {
    int rem = id, Si = 0, Sj = 0, fnd = 0;
    for (int s_j = 0; s_j < 4 && !fnd; ++s_j)
      for (int s_i = 0; s_i <= s_j && !fnd; ++s_i) {
        int sz = (s_i == s_j) ? 136 : 256;
        if (rem < sz) { Si = s_i; Sj = s_j; fnd = 1; }
        else rem -= sz;
      }
    if (Si == Sj) {
      int tj = 0;
      while ((tj + 1) * (tj + 2) / 2 <= rem) ++tj;   // tj <= 15
      int ti = rem - tj * (tj + 1) / 2;
      bi = Si * 16 + ti;
      bj = Sj * 16 + tj;
    } else {
      bi = Si * 16 + (rem & 15);
      bj = Sj * 16 + (rem >> 4);
    }
  }

  int tid  = threadIdx.x;
  int wave = tid >> 6, lane = tid & 63;
  int wr = wave >> 1, wc = wave & 1;     // 2x2 wave grid, 64x64 each
  int quad = lane >> 4, l15 = lane & 15;

  // per-lane fragment pointers: fragment t of A = reps row
  // (bi*128 + wr*64 + t*16 + l15), k-chunk quad -> +quad*8 elems.
  const ushort_t* pA[4];
  const ushort_t* pB[4];
#pragma unroll
  for (int t = 0; t < 4; ++t) {
    pA[t] = reps + (size_t)(bi * 128 + wr * 64 + t * 16 + l15) * DIM + quad * 8;
    pB[t] = reps + (size_t)(bj * 128 + wc * 64 + t * 16 + l15) * DIM + quad * 8;
  }

  f32x4 zero4 = {0.0f, 0.0f, 0.0f, 0.0f};
  f32x4 acc[4][4];
#pragma unroll
  for (int tr = 0; tr < 4; ++tr)
#pragma unroll
    for (int tc = 0; tc < 4; ++tc) acc[tr][tc] = zero4;

#define LOADF(DST, PTRS, KOFF) do {                          \
    DST[0] = *(const short8*)(PTRS[0] + (KOFF));             \
    DST[1] = *(const short8*)(PTRS[1] + (KOFF));             \
    DST[2] = *(const short8*)(PTRS[2] + (KOFF));             \
    DST[3] = *(const short8*)(PTRS[3] + (KOFF));             \
  } while (0)

#define MFMA16(AF, BF) do {                                                \
    _Pragma("unroll")                                                      \
    for (int tr = 0; tr < 4; ++tr)                                         \
      _Pragma("unroll")                                                    \
      for (int tc = 0; tc < 4; ++tc)                                       \
        acc[tr][tc] = __builtin_amdgcn_mfma_f32_16x16x32_bf16(             \
            AF[tr], BF[tc], acc[tr][tc], 0, 0, 0);                         \
  } while (0)

  // double-buffered fragment registers (named X/Y: static indexing only)
  short8 aX[4], bX[4], aY[4], bY[4];
  LOADF(aX, pA, 0);
  LOADF(bX, pB, 0);

#pragma unroll
  for (int kk = 0; kk < NSTEP; kk += 2) {
    LOADF(aY, pA, (kk + 1) * BK);     // prefetch odd step
    LOADF(bY, pB, (kk + 1) * BK);
    MFMA16(aX, bX);                   // compute even step
    if (kk + 2 < NSTEP) {
      LOADF(aX, pA, (kk + 2) * BK);   // prefetch next even step
      LOADF(bX, pB, (kk + 2) * BK);
    }
    MFMA16(aY, bY);                   // compute odd step
  }

  // ---- epilogue: e = exp(sim/T), mask diagonal, row + col sums ----
  // C layout per 16x16 frag: col = l15, row = quad*4 + r  [m89/m91]
  int rowg_base = bi * 128 + wr * 64;
  int colg_base = bj * 128 + wc * 64;

  f32x4 rsum[4];
  float csum[4] = {0.0f, 0.0f, 0.0f, 0.0f};
#pragma unroll
  for (int tr = 0; tr < 4; ++tr) rsum[tr] = zero4;

#pragma unroll
  for (int tr = 0; tr < 4; ++tr) {
    int rowg0 = rowg_base + tr * 16 + quad * 4;
#pragma unroll
    for (int tc = 0; tc < 4; ++tc) {
      int colg = colg_base + tc * 16 + l15;
      f32x4 a = acc[tr][tc];
      f32x4 e;
#pragma unroll
      for (int r = 0; r < 4; ++r) {
        float v = exp2f(a[r] * EXP_SCALE);
        e[r] = ((rowg0 + r) == colg) ? 0.0f : v;
      }
      rsum[tr] += e;
      csum[tc] += e[0] + e[1] + e[2] + e[3];
    }
  }

  // reduce row sums across the 16 lanes sharing `quad` (masks 1,2,4,8)
#pragma unroll
  for (int m = 1; m <= 8; m <<= 1)
#pragma unroll
    for (int tr = 0; tr < 4; ++tr)
#pragma unroll
      for (int r = 0; r < 4; ++r)
        rsum[tr][r] += __shfl_xor(rsum[tr][r], m, 64);

  if (l15 == 0) {
#pragma unroll
    for (int tr = 0; tr < 4; ++tr)
#pragma unroll
      for (int r = 0; r < 4; ++r)
        atomicAdd(&denom[rowg_base + tr * 16 + quad * 4 + r], rsum[tr][r]);
  }

  if (bi != bj) {
    // reduce col sums across quads (masks 16,32)
#pragma unroll
    for (int m = 16; m <= 32; m <<= 1)
#pragma unroll
      for (int tc = 0; tc < 4; ++tc)
        csum[tc] += __shfl_xor(csum[tc], m, 64);
    if (quad == 0) {
#pragma unroll
      for (int tc = 0; tc < 4; ++tc)
        atomicAdd(&denom[colg_base + tc * 16 + l15], csum[tc]);
    }
  }
}

// ---------------------------------------------------------------------------
// Kernel 3: loss = mean over rows of [log(denom) - pos/T]
// ---------------------------------------------------------------------------
__global__ __launch_bounds__(1024) void loss_kernel(
    const float* __restrict__ denom, const float* __restrict__ pos,
    float* __restrict__ out) {
  __shared__ float red[16];
  int tid = threadIdx.x;
  float p = 0.0f;
  for (int r = tid; r < M_ROWS; r += 1024)
    p += logf(denom[r]) - pos[r & (N_ROWS - 1)] * 10.0f;
#pragma unroll
  for (int m = 32; m >= 1; m >>= 1) p += __shfl_xor(p, m, 64);
  if ((tid & 63) == 0) red[tid >> 6] = p;
  __syncthreads();
  if (tid == 0) {
    float s = 0.0f;
#pragma unroll
    for (int i = 0; i < 16; ++i) s += red[i];
    out[0] = s * (1.0f / M_ROWS);
  }
}

extern "C" void kernel_launch(void* const* d_in, const int* in_sizes, int n_in,
                              void* d_out, int out_size, void* d_ws, size_t ws_size,
                              hipStream_t stream) {
  const float* ei = (const float*)d_in[0];
  const float* ej = (const float*)d_in[1];
  float* out = (float*)d_out;

  char* ws = (char*)d_ws;
  ushort_t* reps = (ushort_t*)ws;                                   // 8 MB bf16
  float* denom = (float*)(ws + (size_t)M_ROWS * DIM * 2);           // 32 KB
  float* pos = (float*)(ws + (size_t)M_ROWS * DIM * 2 + M_ROWS * 4);// 16 KB

  norm_kernel<<<N_ROWS / 4, 256, 0, stream>>>(ei, ej, reps, pos, denom);
  sim_kernel<<<NB, 256, 0, stream>>>(reps, denom);
  loss_kernel<<<1, 1024, 0, stream>>>(denom, pos, out);
}

// Round 11
// 136.464 us; speedup vs baseline: 1.7332x; 1.7332x over previous
//
#include <hip/hip_runtime.h>
#include <hip/hip_bf16.h>
#include <math.h>

#define N_ROWS 4096
#define DIM    512
#define M_ROWS 8192
// sim GEMM: 128x128 tiles, 4 waves (2x2 of 64x64), BK=32, 32 KB LDS dbuf,
// 4 blocks/CU. reps stored K-CHUNK-MAJOR so each global_load_lds reads a
// CONTIGUOUS 1KB region (rounds 0-9 post-mortem: the invariant ~7.3 TB/s
// staging rate was the 16x64B-scattered SOURCE, not bytes/sync/occupancy).
#define BK     32
#define NTILE  64            // 8192 / 128
#define NB     2080          // 64*65/2 triangular tiles (2080 % 8 == 0)
#define NSTEP  16            // 512 / 32
// k-chunk-major layout: element (row, kk*32+e) at kk*KSTRIDE + row*32 + e
#define KSTRIDE ((size_t)M_ROWS * 32)
// exp(sim/0.1) = exp2(sim * 10*log2(e))
#define EXP_SCALE 14.4269504088896340736f

typedef unsigned short ushort_t;
typedef __attribute__((ext_vector_type(8))) short short8;
typedef __attribute__((ext_vector_type(4))) float f32x4;

__device__ __forceinline__ ushort_t f2bf(float x) {
  unsigned int bits = __float_as_uint(x);
  unsigned int lsb = (bits >> 16) & 1u;
  bits += 0x7fffu + lsb;
  return (ushort_t)(bits >> 16);
}

__device__ __forceinline__ void store4bf(ushort_t* p, float4 v, float s) {
  union { ushort_t u[4]; uint2 d; } pk;
  pk.u[0] = f2bf(v.x * s);
  pk.u[1] = f2bf(v.y * s);
  pk.u[2] = f2bf(v.z * s);
  pk.u[3] = f2bf(v.w * s);
  *(uint2*)p = pk.d;
}

// async global -> LDS, 16 B/lane (lds dest = wave-uniform base + lane*16)
__device__ __forceinline__ void async16(const ushort_t* g, ushort_t* l) {
  __builtin_amdgcn_global_load_lds(
      (const __attribute__((address_space(1))) void*)g,
      (__attribute__((address_space(3))) void*)l,
      16, 0, 0);
}

// ---------------------------------------------------------------------------
// Kernel 1: per-row L2 normalize; 256-thread blocks, one wave per row-pair.
// Emits reps in K-CHUNK-MAJOR layout; also zeroes denom[].
// ---------------------------------------------------------------------------
__global__ __launch_bounds__(256) void norm_kernel(
    const float* __restrict__ ei, const float* __restrict__ ej,
    ushort_t* __restrict__ reps, float* __restrict__ pos,
    float* __restrict__ denom) {
  int wave = threadIdx.x >> 6;
  int lane = threadIdx.x & 63;
  int b = blockIdx.x * 4 + wave;
  if (lane == 0) {
    denom[b] = 0.0f;
    denom[b + N_ROWS] = 0.0f;
  }
  const float4* pi = (const float4*)(ei + (size_t)b * DIM);
  const float4* pj = (const float4*)(ej + (size_t)b * DIM);
  float4 a0 = pi[lane];
  float4 a1 = pi[lane + 64];
  float4 b0 = pj[lane];
  float4 b1 = pj[lane + 64];

  float si = a0.x*a0.x + a0.y*a0.y + a0.z*a0.z + a0.w*a0.w
           + a1.x*a1.x + a1.y*a1.y + a1.z*a1.z + a1.w*a1.w;
  float sj = b0.x*b0.x + b0.y*b0.y + b0.z*b0.z + b0.w*b0.w
           + b1.x*b1.x + b1.y*b1.y + b1.z*b1.z + b1.w*b1.w;
  float dp = a0.x*b0.x + a0.y*b0.y + a0.z*b0.z + a0.w*b0.w
           + a1.x*b1.x + a1.y*b1.y + a1.z*b1.z + a1.w*b1.w;

#pragma unroll
  for (int m = 32; m >= 1; m >>= 1) {
    si += __shfl_xor(si, m, 64);
    sj += __shfl_xor(sj, m, 64);
    dp += __shfl_xor(dp, m, 64);
  }
  float ii = 1.0f / fmaxf(sqrtf(si), 1e-12f);
  float ij = 1.0f / fmaxf(sqrtf(sj), 1e-12f);
  if (lane == 0) pos[b] = dp * ii * ij;

  // k-chunk-major stores: a0 covers k = lane*4 .. +4 -> chunk lane>>3,
  // within-chunk elem (lane&7)*4; a1 is k+256 -> chunk 8 + (lane>>3).
  ushort_t* ri = reps + (size_t)b * 32;
  ushort_t* rj = reps + (size_t)(b + N_ROWS) * 32;
  int kk0 = lane >> 3;
  int e0  = (lane & 7) * 4;
  store4bf(ri + (size_t)kk0 * KSTRIDE + e0,       a0, ii);
  store4bf(ri + (size_t)(kk0 + 8) * KSTRIDE + e0, a1, ii);
  store4bf(rj + (size_t)kk0 * KSTRIDE + e0,       b0, ij);
  store4bf(rj + (size_t)(kk0 + 8) * KSTRIDE + e0, b1, ij);
}

// ---------------------------------------------------------------------------
// Kernel 2: 128x128-tile fused sim-GEMM + exp + masked row/col reduction.
// Identical structure to the round-8 best-known (73.2 us, absmax 0):
// stage-at-top counted vmcnt(4), 32 KB LDS dbuf, 4 blocks/CU, super-tile
// blob order + chunked XCD remap, both-sides 16B-granule XOR swizzle.
// ONLY change: reps is k-chunk-major, so each async16's 1KB source region
// (16 rows x 64B of one k-chunk) is CONTIGUOUS -> dense coalescing instead
// of 16 scattered 64B segments. The XOR pre-swizzle only permutes 16B slots
// within 64B lines (bits 0-1 of slot), so density is preserved.
// LDS contents / fragment reads / MFMA / epilogue are bit-identical to r8.
// ---------------------------------------------------------------------------
__global__ __launch_bounds__(256) void sim_kernel(
    const ushort_t* __restrict__ reps, float* __restrict__ denom) {
  // chunked XCD remap: XCD x owns logical ids [x*260, (x+1)*260)
  int id = blockIdx.x;
  id = (id & 7) * (NB / 8) + (id >> 3);

  // super-tile blob decode: 4x4 super grid (16x16 tiles each), sj-major,
  // si<=sj; diag super = 136 tiles (16x16 triangle), off-diag = 256.
  int bi, bj;
  {
    int rem = id, Si = 0, Sj = 0, fnd = 0;
    for (int s_j = 0; s_j < 4 && !fnd; ++s_j)
      for (int s_i = 0; s_i <= s_j && !fnd; ++s_i) {
        int sz = (s_i == s_j) ? 136 : 256;
        if (rem < sz) { Si = s_i; Sj = s_j; fnd = 1; }
        else rem -= sz;
      }
    if (Si == Sj) {
      int tj = 0;
      while ((tj + 1) * (tj + 2) / 2 <= rem) ++tj;   // tj <= 15
      int ti = rem - tj * (tj + 1) / 2;
      bi = Si * 16 + ti;
      bj = Sj * 16 + tj;
    } else {
      bi = Si * 16 + (rem & 15);
      bj = Sj * 16 + (rem >> 4);
    }
  }

  __shared__ ushort_t As[2][128 * BK];   // 8 KB per buffer
  __shared__ ushort_t Bs[2][128 * BK];   // total 32 KB -> 4+ blocks/CU by LDS

  int tid  = threadIdx.x;
  int wave = tid >> 6, lane = tid & 63;
  int wr = wave >> 1, wc = wave & 1;     // 2x2 wave grid, 64x64 each
  int quad = lane >> 4, l15 = lane & 15;

  // staging: chunk c covers LDS bytes [c*1024, c*1024+1024) = rows c*16..+15
  // of the tile, within one k-chunk. k-chunk-major source: those 16 rows'
  // 64B slabs are CONTIGUOUS (row*32 elems apart). Source col pre-swizzled
  // so the linear LDS dest holds row r's slot s at (s ^ ((r>>1)&3)).
  int c0 = wave * 2, c1 = c0 + 1;
  int srow  = lane >> 2;                               // row within chunk
  int selem = ((lane & 3) ^ ((srow >> 1) & 3)) * 8;    // swizzled elem offset
  const ushort_t* gA0 = reps + (size_t)(bi * 128 + c0 * 16 + srow) * 32 + selem;
  const ushort_t* gA1 = reps + (size_t)(bi * 128 + c1 * 16 + srow) * 32 + selem;
  const ushort_t* gB0 = reps + (size_t)(bj * 128 + c0 * 16 + srow) * 32 + selem;
  const ushort_t* gB1 = reps + (size_t)(bj * 128 + c1 * 16 + srow) * 32 + selem;

#define STAGE(D, KC) do {                                   \
    size_t o_ = (size_t)(KC) * KSTRIDE;                     \
    async16(gA0 + o_, &As[D][c0 * 512]);                    \
    async16(gA1 + o_, &As[D][c1 * 512]);                    \
    async16(gB0 + o_, &Bs[D][c0 * 512]);                    \
    async16(gB1 + o_, &Bs[D][c1 * 512]);                    \
  } while (0)

  // fragment reads: row = (multiple of 16) + l15 -> (row>>1)&3 == (l15>>1)&3
  int sqr = (quad ^ ((l15 >> 1) & 3)) * 8;

  f32x4 zero4 = {0.0f, 0.0f, 0.0f, 0.0f};
  f32x4 acc[4][4];
#pragma unroll
  for (int tr = 0; tr < 4; ++tr)
#pragma unroll
    for (int tc = 0; tc < 4; ++tc) acc[tr][tc] = zero4;

  // prologue: stage k-chunk 0 into buffer 0
  STAGE(0, 0);

  for (int kk = 0; kk < NSTEP; ++kk) {
    int cur = kk & 1;
    int nc = (kk + 1) & 15;   // wrap at kk=15: dummy stage, never read

    // next chunk's stage first, then counted wait: the 4 allowed-outstanding
    // are the just-issued loads; chunk kk's 4 (issued last iter) are
    // confirmed without draining.
    STAGE(cur ^ 1, nc);
    asm volatile("s_waitcnt vmcnt(4)" ::: "memory");
    __builtin_amdgcn_s_barrier();   // buf[cur] valid for all waves

    short8 aF[4], bF[4];
#pragma unroll
    for (int t = 0; t < 4; ++t) {
      aF[t] = *(const short8*)(&As[cur][(wr * 64 + t * 16 + l15) * BK + sqr]);
      bF[t] = *(const short8*)(&Bs[cur][(wc * 64 + t * 16 + l15) * BK + sqr]);
    }
    __builtin_amdgcn_s_setprio(1);
#pragma unroll
    for (int tr = 0; tr < 4; ++tr)
#pragma unroll
      for (int tc = 0; tc < 4; ++tc)
        acc[tr][tc] = __builtin_amdgcn_mfma_f32_16x16x32_bf16(
            aF[tr], bF[tc], acc[tr][tc], 0, 0, 0);
    __builtin_amdgcn_s_setprio(0);
    __builtin_amdgcn_s_barrier();   // all reads of buf[cur] done before its
                                    // overwrite (staged next iteration)
  }
  // drain the kk=15 dummy stages before LDS goes dead
  asm volatile("s_waitcnt vmcnt(0)" ::: "memory");

  // ---- epilogue: e = exp(sim/T), mask diagonal, row + col sums ----
  // C layout per 16x16 frag: col = l15, row = quad*4 + r  [m89/m91]
  int rowg_base = bi * 128 + wr * 64;
  int colg_base = bj * 128 + wc * 64;

  f32x4 rsum[4];
  float csum[4] = {0.0f, 0.0f, 0.0f, 0.0f};
#pragma unroll
  for (int tr = 0; tr < 4; ++tr) rsum[tr] = zero4;

#pragma unroll
  for (int tr = 0; tr < 4; ++tr) {
    int rowg0 = rowg_base + tr * 16 + quad * 4;
#pragma unroll
    for (int tc = 0; tc < 4; ++tc) {
      int colg = colg_base + tc * 16 + l15;
      f32x4 a = acc[tr][tc];
      f32x4 e;
#pragma unroll
      for (int r = 0; r < 4; ++r) {
        float v = exp2f(a[r] * EXP_SCALE);
        e[r] = ((rowg0 + r) == colg) ? 0.0f : v;
      }
      rsum[tr] += e;
      csum[tc] += e[0] + e[1] + e[2] + e[3];
    }
  }

  // reduce row sums across the 16 lanes sharing `quad` (masks 1,2,4,8)
#pragma unroll
  for (int m = 1; m <= 8; m <<= 1)
#pragma unroll
    for (int tr = 0; tr < 4; ++tr)
#pragma unroll
      for (int r = 0; r < 4; ++r)
        rsum[tr][r] += __shfl_xor(rsum[tr][r], m, 64);

  if (l15 == 0) {
#pragma unroll
    for (int tr = 0; tr < 4; ++tr)
#pragma unroll
      for (int r = 0; r < 4; ++r)
        atomicAdd(&denom[rowg_base + tr * 16 + quad * 4 + r], rsum[tr][r]);
  }

  if (bi != bj) {
    // reduce col sums across quads (masks 16,32)
#pragma unroll
    for (int m = 16; m <= 32; m <<= 1)
#pragma unroll
      for (int tc = 0; tc < 4; ++tc)
        csum[tc] += __shfl_xor(csum[tc], m, 64);
    if (quad == 0) {
#pragma unroll
      for (int tc = 0; tc < 4; ++tc)
        atomicAdd(&denom[colg_base + tc * 16 + l15], csum[tc]);
    }
  }
}

// ---------------------------------------------------------------------------
// Kernel 3: loss = mean over rows of [log(denom) - pos/T]
// ---------------------------------------------------------------------------
__global__ __launch_bounds__(1024) void loss_kernel(
    const float* __restrict__ denom, const float* __restrict__ pos,
    float* __restrict__ out) {
  __shared__ float red[16];
  int tid = threadIdx.x;
  float p = 0.0f;
  for (int r = tid; r < M_ROWS; r += 1024)
    p += logf(denom[r]) - pos[r & (N_ROWS - 1)] * 10.0f;
#pragma unroll
  for (int m = 32; m >= 1; m >>= 1) p += __shfl_xor(p, m, 64);
  if ((tid & 63) == 0) red[tid >> 6] = p;
  __syncthreads();
  if (tid == 0) {
    float s = 0.0f;
#pragma unroll
    for (int i = 0; i < 16; ++i) s += red[i];
    out[0] = s * (1.0f / M_ROWS);
  }
}

extern "C" void kernel_launch(void* const* d_in, const int* in_sizes, int n_in,
                              void* d_out, int out_size, void* d_ws, size_t ws_size,
                              hipStream_t stream) {
  const float* ei = (const float*)d_in[0];
  const float* ej = (const float*)d_in[1];
  float* out = (float*)d_out;

  char* ws = (char*)d_ws;
  ushort_t* reps = (ushort_t*)ws;                                   // 8 MB bf16
  float* denom = (float*)(ws + (size_t)M_ROWS * DIM * 2);           // 32 KB
  float* pos = (float*)(ws + (size_t)M_ROWS * DIM * 2 + M_ROWS * 4);// 16 KB

  norm_kernel<<<N_ROWS / 4, 256, 0, stream>>>(ei, ej, reps, pos, denom);
  sim_kernel<<<NB, 256, 0, stream>>>(reps, denom);
  loss_kernel<<<1, 1024, 0, stream>>>(denom, pos, out);
}